// Round 3
// baseline (453.874 us; speedup 1.0000x reference)
//
#include <hip/hip_runtime.h>
#include <stdint.h>

// out[(b,m),n] = (sum_k x_q[(b,m),k] * w[n,k]) * sx[(b,m)] * ws[n] + bias[n]
// Integer inputs arrive as int32 buffers; pass 1 packs to int8 in d_ws,
// pass 2 is a 128x128-tile i8 MFMA GEMM using v_mfma_i32_32x32x32_i8.
#define MROWS 8192
#define K_DIM 4096
#define N_DIM 4096
#define BM 128
#define BN 128
#define BK 64   // bytes of K per stage

#define X_ELEMS (MROWS * K_DIM)
#define W_ELEMS (N_DIM * K_DIM)

typedef __attribute__((ext_vector_type(4)))  int int4v;
typedef __attribute__((ext_vector_type(16))) int int16v;

#define GLOAD_LDS16(gptr, lptr)                                                   \
    __builtin_amdgcn_global_load_lds((const __attribute__((address_space(1))) void*)(gptr), \
                                     (__attribute__((address_space(3))) void*)(lptr), 16, 0, 0)

// ---- pass 1: int32 -> packed int8, 16 elems (64 B read -> 16 B write) / lane --
__device__ __forceinline__ int pack4(int4v v) {
    return (int)((unsigned)(v[0] & 0xFF)
               | ((unsigned)(v[1] & 0xFF) << 8)
               | ((unsigned)(v[2] & 0xFF) << 16)
               | ((unsigned)(v[3] & 0xFF) << 24));
}

__global__ __launch_bounds__(256) void pack_i32_to_i8(
    const int4v* __restrict__ src, int4v* __restrict__ dst, int n16)
{
    int i = blockIdx.x * blockDim.x + threadIdx.x;
    if (i >= n16) return;
    int4v a = src[4 * i + 0];
    int4v b = src[4 * i + 1];
    int4v c = src[4 * i + 2];
    int4v d = src[4 * i + 3];
    int4v r;
    r[0] = pack4(a); r[1] = pack4(b); r[2] = pack4(c); r[3] = pack4(d);
    dst[i] = r;
}

// ---- pass 2: i8 GEMM (32x32x32 MFMA) + dequant epilogue ---------------------
__global__ __launch_bounds__(256) void i8gemm_dq_kernel(
    const int8_t* __restrict__ xq,   // (8192, 4096) packed i8
    const float*  __restrict__ sx,   // (8192,)
    const int8_t* __restrict__ wt,   // (4096, 4096) packed i8 (row = n)
    const float*  __restrict__ ws,   // (4096,)
    const float*  __restrict__ bias, // (4096,)
    float*        __restrict__ out)  // (8192, 4096) f32
{
    __shared__ __align__(16) int8_t lsA[BM * BK];  // 8 KB
    __shared__ __align__(16) int8_t lsB[BN * BK];  // 8 KB

    const int tid  = threadIdx.x;
    const int wave = tid >> 6;
    const int lane = tid & 63;

    const int ct = blockIdx.x & 31;   // 32 consecutive blocks share a row tile
    const int rt = blockIdx.x >> 5;

    const int wr = wave >> 1;   // 64-row half
    const int wc = wave & 1;    // 64-col half

    // staging: 64 lanes x 16 B = 16 rows/instruction, row-major stride BK
    const int srow = wave * 16 + (lane >> 2);
    const int scol = (lane & 3) * 16;
    const int8_t* gA = xq + (size_t)(rt * BM + srow) * K_DIM + scol;
    const int8_t* gB = wt + (size_t)(ct * BN + srow) * K_DIM + scol;
    int8_t* lA = lsA + wave * 1024;
    int8_t* lB = lsB + wave * 1024;

    // A/B frag for 32x32x32 i8: lane holds 16 contiguous K-bytes of row
    // (lane&31), K-half (lane>>5)*16.
    const int m32   = lane & 31;
    const int khalf = (lane >> 5) * 16;

    int16v acc[2][2] = {};   // 2x2 of 32x32 int32 tiles per wave (64 AGPRs)

    const int kIters = K_DIM / BK;  // 64
    for (int kt = 0; kt < kIters; ++kt) {
        GLOAD_LDS16(gA,              lA);
        GLOAD_LDS16(gA + 64 * K_DIM, lA + 4096);
        GLOAD_LDS16(gB,              lB);
        GLOAD_LDS16(gB + 64 * K_DIM, lB + 4096);
        gA += BK;
        gB += BK;
        __syncthreads();

        int4v af[2][2], bf[2][2];   // [tile][kstep]
        #pragma unroll
        for (int i = 0; i < 2; ++i)
            #pragma unroll
            for (int s = 0; s < 2; ++s)
                af[i][s] = *(const int4v*)(lsA + (wr * 64 + i * 32 + m32) * BK + s * 32 + khalf);
        #pragma unroll
        for (int j = 0; j < 2; ++j)
            #pragma unroll
            for (int s = 0; s < 2; ++s)
                bf[j][s] = *(const int4v*)(lsB + (wc * 64 + j * 32 + m32) * BK + s * 32 + khalf);

        #pragma unroll
        for (int s = 0; s < 2; ++s)
            #pragma unroll
            for (int i = 0; i < 2; ++i)
                #pragma unroll
                for (int j = 0; j < 2; ++j)
                    acc[i][j] = __builtin_amdgcn_mfma_i32_32x32x32_i8(
                                    af[i][s], bf[j][s], acc[i][j], 0, 0, 0);

        __syncthreads();
    }

    // epilogue: C/D 32x32 layout col=lane&31, row=(reg&3)+8*(reg>>2)+4*(lane>>5)
    const int row_base = rt * BM + wr * 64;
    const int col_base = ct * BN + wc * 64;
    const int ccol  = lane & 31;
    const int rquad = (lane >> 5) * 4;

    float wsc[2], bsc[2];
    #pragma unroll
    for (int j = 0; j < 2; ++j) {
        const int c = col_base + j * 32 + ccol;
        wsc[j] = ws[c];
        bsc[j] = bias[c];
    }

    #pragma unroll
    for (int i = 0; i < 2; ++i) {
        float sxv[16];
        #pragma unroll
        for (int reg = 0; reg < 16; ++reg) {
            const int r = row_base + i * 32 + (reg & 3) + 8 * (reg >> 2) + rquad;
            sxv[reg] = sx[r];
        }
        #pragma unroll
        for (int j = 0; j < 2; ++j) {
            const int c = col_base + j * 32 + ccol;
            #pragma unroll
            for (int reg = 0; reg < 16; ++reg) {
                const int r = row_base + i * 32 + (reg & 3) + 8 * (reg >> 2) + rquad;
                out[(size_t)r * N_DIM + c] = (float)acc[i][j][reg] * sxv[reg] * wsc[j] + bsc[j];
            }
        }
    }
}

extern "C" void kernel_launch(void* const* d_in, const int* in_sizes, int n_in,
                              void* d_out, int out_size, void* d_ws, size_t ws_size,
                              hipStream_t stream) {
    const int*   xq32 = (const int*)d_in[0];
    const float* sx   = (const float*)d_in[1];
    const int*   wt32 = (const int*)d_in[2];
    const float* ws   = (const float*)d_in[3];
    const float* bias = (const float*)d_in[4];
    float* out = (float*)d_out;

    int8_t* xq8 = (int8_t*)d_ws;
    int8_t* wt8 = xq8 + (size_t)X_ELEMS;

    {
        int n16x = X_ELEMS / 16;   // 2,097,152 -> 8192 blocks
        int n16w = W_ELEMS / 16;   // 1,048,576 -> 4096 blocks
        pack_i32_to_i8<<<n16x / 256, 256, 0, stream>>>((const int4v*)xq32, (int4v*)xq8, n16x);
        pack_i32_to_i8<<<n16w / 256, 256, 0, stream>>>((const int4v*)wt32, (int4v*)wt8, n16w);
    }

    dim3 grid((MROWS / BM) * (N_DIM / BN));  // 2048 blocks
    i8gemm_dq_kernel<<<grid, 256, 0, stream>>>(xq8, sx, wt8, ws, bias, out);
}

// Round 4
// 414.579 us; speedup vs baseline: 1.0948x; 1.0948x over previous
//
#include <hip/hip_runtime.h>
#include <stdint.h>

// out[(b,m),n] = (sum_k x_q[(b,m),k] * w[n,k]) * sx[(b,m)] * ws[n] + bias[n]
// Integer inputs arrive as int32 buffers; pass 1 packs to int8 in d_ws,
// pass 2 is a 128x128-tile i8 MFMA GEMM (16x16x64) with a 16B-chunk XOR
// swizzle on the LDS layout to eliminate ds_read_b128 bank conflicts.
#define MROWS 8192
#define K_DIM 4096
#define N_DIM 4096
#define BM 128
#define BN 128
#define BK 64   // bytes of K per stage

#define X_ELEMS (MROWS * K_DIM)
#define W_ELEMS (N_DIM * K_DIM)

typedef __attribute__((ext_vector_type(4))) int int4v;

#define GLOAD_LDS16(gptr, lptr)                                                   \
    __builtin_amdgcn_global_load_lds((const __attribute__((address_space(1))) void*)(gptr), \
                                     (__attribute__((address_space(3))) void*)(lptr), 16, 0, 0)

// ---- pass 1: int32 -> packed int8, 16 elems (64 B read -> 16 B write) / lane --
__device__ __forceinline__ int pack4(int4v v) {
    return (int)((unsigned)(v[0] & 0xFF)
               | ((unsigned)(v[1] & 0xFF) << 8)
               | ((unsigned)(v[2] & 0xFF) << 16)
               | ((unsigned)(v[3] & 0xFF) << 24));
}

__global__ __launch_bounds__(256) void pack_i32_to_i8(
    const int4v* __restrict__ src, int4v* __restrict__ dst, int n16)
{
    int i = blockIdx.x * blockDim.x + threadIdx.x;
    if (i >= n16) return;
    int4v a = src[4 * i + 0];
    int4v b = src[4 * i + 1];
    int4v c = src[4 * i + 2];
    int4v d = src[4 * i + 3];
    int4v r;
    r[0] = pack4(a); r[1] = pack4(b); r[2] = pack4(c); r[3] = pack4(d);
    dst[i] = r;
}

// ---- pass 2: i8 GEMM (16x16x64 MFMA) + dequant epilogue ---------------------
// LDS swizzle: 16B chunk c (0..3) of tile row r stored at slot (c + (r>>1)) & 3.
// Staging fetches global chunk (slot - (r>>1)) & 3 so the hardware's fixed
// lane*16 LDS placement realizes the swizzle. Frag reads then hit each 4-bank
// group exactly twice per quarter-wave (2-way = free, vs 8-way unswizzled).
__global__ __launch_bounds__(256) void i8gemm_dq_kernel(
    const int8_t* __restrict__ xq,   // (8192, 4096) packed i8
    const float*  __restrict__ sx,   // (8192,)
    const int8_t* __restrict__ wt,   // (4096, 4096) packed i8 (row = n)
    const float*  __restrict__ ws,   // (4096,)
    const float*  __restrict__ bias, // (4096,)
    float*        __restrict__ out)  // (8192, 4096) f32
{
    __shared__ __align__(16) int8_t lsA[BM * BK];  // 8 KB
    __shared__ __align__(16) int8_t lsB[BN * BK];  // 8 KB

    const int tid  = threadIdx.x;
    const int wave = tid >> 6;
    const int lane = tid & 63;

    const int ct = blockIdx.x & 31;   // 32 consecutive blocks share a row tile
    const int rt = blockIdx.x >> 5;

    const int wr = wave >> 1;   // 64-row half
    const int wc = wave & 1;    // 64-col half

    // staging: lane covers LDS slot (row = wave*16 + lane>>2, cslot = lane&3).
    // Fetch global chunk c = (cslot - (row>>1)) & 3; (row>>1)&3 == (lane>>3)&3
    // for both 64-row passes, so the swizzle is lane-only.
    const int srow = wave * 16 + (lane >> 2);
    const int scol = (((lane & 3) - ((lane >> 3) & 3)) & 3) * 16;
    const int8_t* gA = xq + (size_t)(rt * BM + srow) * K_DIM + scol;
    const int8_t* gB = wt + (size_t)(ct * BN + srow) * K_DIM + scol;
    int8_t* lA = lsA + wave * 1024;
    int8_t* lB = lsB + wave * 1024;

    // frag read: lane wants chunk c = lane>>4 of row (lane&15); stored slot =
    // (c + (row>>1)) & 3, and (row>>1)&3 == ((lane&15)>>1)&3 (row base is a
    // multiple of 16).
    const int mrow = lane & 15;
    const int kswz = ((((lane >> 4) + (mrow >> 1)) & 3)) * 16;

    int4v acc[4][4] = {};   // 4x4 of 16x16 int32 accumulators per wave

    const int kIters = K_DIM / BK;  // 64
    for (int kt = 0; kt < kIters; ++kt) {
        GLOAD_LDS16(gA,              lA);
        GLOAD_LDS16(gA + 64 * K_DIM, lA + 4096);
        GLOAD_LDS16(gB,              lB);
        GLOAD_LDS16(gB + 64 * K_DIM, lB + 4096);
        gA += BK;
        gB += BK;
        __syncthreads();   // drains vmcnt -> LDS tiles valid

        int4v afrag[4], bfrag[4];
        #pragma unroll
        for (int i = 0; i < 4; ++i)
            afrag[i] = *(const int4v*)(lsA + (wr * 64 + i * 16 + mrow) * BK + kswz);
        #pragma unroll
        for (int j = 0; j < 4; ++j)
            bfrag[j] = *(const int4v*)(lsB + (wc * 64 + j * 16 + mrow) * BK + kswz);

        #pragma unroll
        for (int i = 0; i < 4; ++i)
            #pragma unroll
            for (int j = 0; j < 4; ++j)
                acc[i][j] = __builtin_amdgcn_mfma_i32_16x16x64_i8(
                                afrag[i], bfrag[j], acc[i][j], 0, 0, 0);

        __syncthreads();   // before next stage overwrites LDS
    }

    // epilogue: C/D layout col=lane&15, row=(lane>>4)*4+reg
    const int row_base = rt * BM + wr * 64;
    const int col_base = ct * BN + wc * 64;
    const int crow = (lane >> 4) * 4;
    const int ccol = lane & 15;

    float wsc[4], bsc[4];
    #pragma unroll
    for (int j = 0; j < 4; ++j) {
        const int c = col_base + j * 16 + ccol;
        wsc[j] = ws[c];
        bsc[j] = bias[c];
    }

    #pragma unroll
    for (int i = 0; i < 4; ++i) {
        const int r0 = row_base + i * 16 + crow;
        float sx4[4];
        #pragma unroll
        for (int r = 0; r < 4; ++r) sx4[r] = sx[r0 + r];
        #pragma unroll
        for (int j = 0; j < 4; ++j) {
            const int c = col_base + j * 16 + ccol;
            float* o = out + (size_t)r0 * N_DIM + c;
            #pragma unroll
            for (int r = 0; r < 4; ++r)
                o[(size_t)r * N_DIM] = (float)acc[i][j][r] * sx4[r] * wsc[j] + bsc[j];
        }
    }
}

extern "C" void kernel_launch(void* const* d_in, const int* in_sizes, int n_in,
                              void* d_out, int out_size, void* d_ws, size_t ws_size,
                              hipStream_t stream) {
    const int*   xq32 = (const int*)d_in[0];
    const float* sx   = (const float*)d_in[1];
    const int*   wt32 = (const int*)d_in[2];
    const float* ws   = (const float*)d_in[3];
    const float* bias = (const float*)d_in[4];
    float* out = (float*)d_out;

    int8_t* xq8 = (int8_t*)d_ws;
    int8_t* wt8 = xq8 + (size_t)X_ELEMS;

    {
        int n16x = X_ELEMS / 16;
        int n16w = W_ELEMS / 16;
        pack_i32_to_i8<<<n16x / 256, 256, 0, stream>>>((const int4v*)xq32, (int4v*)xq8, n16x);
        pack_i32_to_i8<<<n16w / 256, 256, 0, stream>>>((const int4v*)wt32, (int4v*)wt8, n16w);
    }

    dim3 grid((MROWS / BM) * (N_DIM / BN));  // 2048 blocks
    i8gemm_dq_kernel<<<grid, 256, 0, stream>>>(xq8, sx, wt8, ws, bias, out);
}